// Round 5
// baseline (16400.784 us; speedup 1.0000x reference)
//
#include <hip/hip_runtime.h>
#include <math.h>

#define SS 2000
#define DMM 512
#define HHN 4
#define DKK 512
#define HDK 2048
#define NLL 32
#define HNL 128
#define GGN 200
#define WSZ 10
#define TTN 20
#define EXTT 5

// ---------------- block reduction helper (256 threads) ----------------
__device__ __forceinline__ float block_sum256(float v, float* sh) {
  #pragma unroll
  for (int off = 32; off > 0; off >>= 1) v += __shfl_down(v, off);
  if ((threadIdx.x & 63) == 0) sh[threadIdx.x >> 6] = v;
  __syncthreads();
  float t = sh[0] + sh[1] + sh[2] + sh[3];
  __syncthreads();
  return t;
}

// ---------------- GEMM: C = (A[M,K] @ W[K,N] + bias)*alpha, M-guarded -------
// BM=128 BN=64 BK=16, 256 threads, each thread 8x4. N%64==0, K%16==0.
__global__ __launch_bounds__(256)
void gemm_f32(const float* __restrict__ A, const float* __restrict__ W,
              const float* __restrict__ bias, float* __restrict__ Cout,
              int M, int N, int K, float alpha) {
  const int BM = 128, BN = 64, BK = 16;
  __shared__ float As[BK][BM];
  __shared__ float Ws[BK][BN];
  int bm = blockIdx.y * BM, bn = blockIdx.x * BN;
  int tid = threadIdx.x;
  int tc = tid & 15, tr = tid >> 4;
  float acc[8][4];
  #pragma unroll
  for (int i = 0; i < 8; ++i)
    #pragma unroll
    for (int j = 0; j < 4; ++j) acc[i][j] = 0.f;

  for (int k0 = 0; k0 < K; k0 += BK) {
    #pragma unroll
    for (int i = tid; i < BM * BK / 4; i += 256) {
      int r = i >> 2;
      int c4 = (i & 3) << 2;
      int row = bm + r;
      float4 v = make_float4(0.f, 0.f, 0.f, 0.f);
      if (row < M) v = *(const float4*)&A[(size_t)row * K + k0 + c4];
      As[c4 + 0][r] = v.x; As[c4 + 1][r] = v.y;
      As[c4 + 2][r] = v.z; As[c4 + 3][r] = v.w;
    }
    {
      int r = tid >> 4;
      int c4 = (tid & 15) << 2;
      *(float4*)&Ws[r][c4] = *(const float4*)&W[(size_t)(k0 + r) * N + bn + c4];
    }
    __syncthreads();
    #pragma unroll
    for (int kk = 0; kk < BK; ++kk) {
      float a[8], w[4];
      *(float4*)&a[0] = *(const float4*)&As[kk][tr * 8];
      *(float4*)&a[4] = *(const float4*)&As[kk][tr * 8 + 4];
      *(float4*)&w[0] = *(const float4*)&Ws[kk][tc * 4];
      #pragma unroll
      for (int i = 0; i < 8; ++i)
        #pragma unroll
        for (int j = 0; j < 4; ++j) acc[i][j] = fmaf(a[i], w[j], acc[i][j]);
    }
    __syncthreads();
  }
  int c = bn + tc * 4;
  float4 bv = *(const float4*)&bias[c];
  #pragma unroll
  for (int i = 0; i < 8; ++i) {
    int r = bm + tr * 8 + i;
    if (r < M) {
      float4 o;
      o.x = (acc[i][0] + bv.x) * alpha;
      o.y = (acc[i][1] + bv.y) * alpha;
      o.z = (acc[i][2] + bv.z) * alpha;
      o.w = (acc[i][3] + bv.w) * alpha;
      *(float4*)&Cout[(size_t)r * N + c] = o;
    }
  }
}

// ---------------- LayerNorm over fp32 rows of 2048 (in place) ---------------
__global__ __launch_bounds__(256)
void ln_row2048(float* __restrict__ Y, const float* __restrict__ gam,
                const float* __restrict__ bet) {
  __shared__ float sh[4];
  float* y = Y + (size_t)blockIdx.x * HDK;
  int t = threadIdx.x;
  float v[8];
  *(float4*)&v[0] = *(const float4*)&y[t * 8];
  *(float4*)&v[4] = *(const float4*)&y[t * 8 + 4];
  float s = 0.f;
  #pragma unroll
  for (int j = 0; j < 8; ++j) s += v[j];
  s = block_sum256(s, sh);
  float mean = s * (1.f / 2048.f);
  float ss = 0.f;
  #pragma unroll
  for (int j = 0; j < 8; ++j) { float d = v[j] - mean; ss = fmaf(d, d, ss); }
  ss = block_sum256(ss, sh);
  float rstd = rsqrtf(ss * (1.f / 2048.f) + 1e-5f);
  float gg[8], bb[8];
  *(float4*)&gg[0] = *(const float4*)&gam[t * 8];
  *(float4*)&gg[4] = *(const float4*)&gam[t * 8 + 4];
  *(float4*)&bb[0] = *(const float4*)&bet[t * 8];
  *(float4*)&bb[4] = *(const float4*)&bet[t * 8 + 4];
  float o[8];
  #pragma unroll
  for (int j = 0; j < 8; ++j) o[j] = (v[j] - mean) * rstd * gg[j] + bb[j];
  *(float4*)&y[t * 8]     = *(float4*)&o[0];
  *(float4*)&y[t * 8 + 4] = *(float4*)&o[4];
}

// ---------------- softmax over s of hs[s][128] (one batch, grid=1) ----------
__global__ __launch_bounds__(1024)
void hs_softmax_f32(float* __restrict__ hs, const float* __restrict__ mask) {
  int c = threadIdx.x;      // 0..127 column
  int ysl = threadIdx.y;    // 0..7  s stripe
  __shared__ float red[8][128];
  float mx = -INFINITY;
  for (int s = ysl; s < SS; s += 8) {
    float m = mask[s];
    float val = (m != 0.f) ? hs[(size_t)s * HNL + c] : -INFINITY;
    mx = fmaxf(mx, val);
  }
  red[ysl][c] = mx; __syncthreads();
  mx = red[0][c];
  #pragma unroll
  for (int i = 1; i < 8; ++i) mx = fmaxf(mx, red[i][c]);
  __syncthreads();
  float sum = 0.f;
  for (int s = ysl; s < SS; s += 8) {
    float m = mask[s];
    if (m != 0.f) sum += expf(hs[(size_t)s * HNL + c] - mx);
  }
  red[ysl][c] = sum; __syncthreads();
  sum = 0.f;
  #pragma unroll
  for (int i = 0; i < 8; ++i) sum += red[i][c];
  float inv = 1.f / sum;
  for (int s = ysl; s < SS; s += 8) {
    size_t idx = (size_t)s * HNL + c;
    float m = mask[s];
    hs[idx] = (m != 0.f) ? expf(hs[idx] - mx) * inv : 0.f;
  }
}

// ---------------- compression: Kc/Vc[(h*32+l)*512+d] = sum_s hs*K/V ---------
__global__ __launch_bounds__(256)
void compress_f32(const float* __restrict__ Kf, const float* __restrict__ Vf,
                  const float* __restrict__ hs, float* __restrict__ Kc,
                  float* __restrict__ Vc) {
  int dchunk = blockIdx.x & 1;
  int h = blockIdx.x >> 1;            // [0,4)
  int d = dchunk * 256 + threadIdx.x; // [0,512)
  float ak[NLL], av[NLL];
  #pragma unroll
  for (int l = 0; l < NLL; ++l) { ak[l] = 0.f; av[l] = 0.f; }
  __shared__ float hsh[16][32];
  for (int s0 = 0; s0 < SS; s0 += 16) {
    for (int i = threadIdx.x; i < 512; i += 256) {
      int si = i >> 5, l = i & 31;
      hsh[si][l] = hs[(size_t)(s0 + si) * HNL + h * NLL + l];
    }
    __syncthreads();
    for (int si = 0; si < 16; ++si) {
      float kv = Kf[(size_t)(s0 + si) * HDK + h * DKK + d];
      float vv = Vf[(size_t)(s0 + si) * HDK + h * DKK + d];
      #pragma unroll
      for (int l = 0; l < NLL; ++l) {
        float hw = hsh[si][l];
        ak[l] = fmaf(hw, kv, ak[l]);
        av[l] = fmaf(hw, vv, av[l]);
      }
    }
    __syncthreads();
  }
  #pragma unroll
  for (int l = 0; l < NLL; ++l) {
    Kc[(size_t)(h * NLL + l) * DKK + d] = ak[l];
    Vc[(size_t)(h * NLL + l) * DKK + d] = av[l];
  }
}

// ---------------- LN over f=h*512+d for row l of Kc/Vc (in place) -----------
__global__ __launch_bounds__(256)
void ln_comp_f32(float* __restrict__ Y, const float* __restrict__ gam,
                 const float* __restrict__ bet) {
  __shared__ float sh[4];
  int l = blockIdx.x;                 // [0,32)
  float v[8]; float s = 0.f;
  #pragma unroll
  for (int j = 0; j < 8; ++j) {
    int f = threadIdx.x + 256 * j;    // [0,2048)
    int hh = f >> 9, dd = f & 511;
    v[j] = Y[(size_t)(hh * NLL + l) * DKK + dd];
    s += v[j];
  }
  s = block_sum256(s, sh);
  float mean = s * (1.f / 2048.f);
  float ss = 0.f;
  #pragma unroll
  for (int j = 0; j < 8; ++j) { float d = v[j] - mean; ss = fmaf(d, d, ss); }
  ss = block_sum256(ss, sh);
  float rstd = rsqrtf(ss * (1.f / 2048.f) + 1e-5f);
  #pragma unroll
  for (int j = 0; j < 8; ++j) {
    int f = threadIdx.x + 256 * j;
    int hh = f >> 9, dd = f & 511;
    Y[(size_t)(hh * NLL + l) * DKK + dd] = (v[j] - mean) * rstd * gam[f] + bet[f];
  }
}

// ---------------- fused attention per (h,g), one batch ----------------------
// Cf is a SEPARATE buffer (no aliasing).
__global__ __launch_bounds__(256)
void attn_f32(const float* __restrict__ Qf, const float* __restrict__ Kf,
              const float* __restrict__ Vf, const float* __restrict__ Kc,
              const float* __restrict__ Vc, const float* __restrict__ mask,
              float* __restrict__ Cf) {
  int g = blockIdx.x % GGN;
  int h = blockIdx.x / GGN;
  __shared__ float Qh[WSZ][260];
  __shared__ float KVh[TTN][260];
  __shared__ float sc[WSZ][64];   // 52 used
  __shared__ float colvalid[TTN];
  int tid = threadIdx.x;
  if (tid < TTN) {
    int j = g * WSZ + tid - EXTT;
    colvalid[tid] = (j >= 0 && j < SS && mask[j] != 0.f) ? 1.f : 0.f;
  }
  // compress scores: 320 = 10w x 32c entries -> e = tid (all) and e = tid+256 (tid<64)
  // window scores: 200 = 10w x 20t entries -> tid < 200
  float accC0 = 0.f, accC1 = 0.f, accW = 0.f;
  for (int dh = 0; dh < 2; ++dh) {
    for (int i = tid; i < WSZ * 64; i += 256) {
      int w = i >> 6, d4 = (i & 63) << 2;
      *(float4*)&Qh[w][d4] =
          *(const float4*)&Qf[(size_t)(g * WSZ + w) * HDK + h * DKK + dh * 256 + d4];
    }
    for (int i = tid; i < TTN * 64; i += 256) {
      int t = i >> 6, d4 = (i & 63) << 2;
      int j = g * WSZ + t - EXTT;
      float4 v = make_float4(0.f, 0.f, 0.f, 0.f);
      if (j >= 0 && j < SS)
        v = *(const float4*)&Kf[(size_t)j * HDK + h * DKK + dh * 256 + d4];
      *(float4*)&KVh[t][d4] = v;
    }
    __syncthreads();
    {
      int w = tid >> 5, c = tid & 31;
      const float* kp = Kc + ((size_t)(h * NLL + c) * DKK + dh * 256);
      const float* qp = &Qh[w][0];
      float a = 0.f;
      #pragma unroll 8
      for (int d = 0; d < 256; ++d) a = fmaf(qp[d], kp[d], a);
      accC0 += a;
    }
    if (tid < 64) {
      int w = 8 + (tid >> 5), c = tid & 31;
      const float* kp = Kc + ((size_t)(h * NLL + c) * DKK + dh * 256);
      const float* qp = &Qh[w][0];
      float a = 0.f;
      #pragma unroll 8
      for (int d = 0; d < 256; ++d) a = fmaf(qp[d], kp[d], a);
      accC1 += a;
    }
    if (tid < 200) {
      int w = tid / 20, t = tid % 20;
      const float* kp = &KVh[t][0];
      const float* qp = &Qh[w][0];
      float a = 0.f;
      #pragma unroll 8
      for (int d = 0; d < 256; ++d) a = fmaf(qp[d], kp[d], a);
      accW += a;
    }
    __syncthreads();
  }
  { int w = tid >> 5, c = tid & 31; sc[w][c] = accC0; }
  if (tid < 64) { int w = 8 + (tid >> 5), c = tid & 31; sc[w][c] = accC1; }
  if (tid < 200) {
    int w = tid / 20, t = tid % 20;
    sc[w][NLL + t] = (colvalid[t] != 0.f) ? accW : -INFINITY;
  }
  __syncthreads();
  if (tid < WSZ) {
    float mx = -INFINITY;
    for (int c = 0; c < 52; ++c) mx = fmaxf(mx, sc[tid][c]);
    float sum = 0.f;
    for (int c = 0; c < 52; ++c) { float e = expf(sc[tid][c] - mx); sc[tid][c] = e; sum += e; }
    float qm = mask[g * WSZ + tid];
    float inv = (qm != 0.f) ? 1.f / sum : 0.f;
    for (int c = 0; c < 52; ++c) sc[tid][c] *= inv;
  }
  __syncthreads();
  for (int dh = 0; dh < 2; ++dh) {
    for (int i = tid; i < TTN * 64; i += 256) {
      int t = i >> 6, d4 = (i & 63) << 2;
      int j = g * WSZ + t - EXTT;
      float4 v = make_float4(0.f, 0.f, 0.f, 0.f);
      if (j >= 0 && j < SS)
        v = *(const float4*)&Vf[(size_t)j * HDK + h * DKK + dh * 256 + d4];
      *(float4*)&KVh[t][d4] = v;
    }
    __syncthreads();
    int d = tid;  // [0,256)
    const float* vcb = Vc + (size_t)h * NLL * DKK + dh * 256 + d;
    for (int w = 0; w < WSZ; ++w) {
      float acc = 0.f;
      #pragma unroll 8
      for (int l = 0; l < NLL; ++l) acc = fmaf(sc[w][l], vcb[(size_t)l * DKK], acc);
      #pragma unroll
      for (int t = 0; t < TTN; ++t) acc = fmaf(sc[w][NLL + t], KVh[t][d], acc);
      Cf[(size_t)(g * WSZ + w) * HDK + h * DKK + dh * 256 + d] = acc;
    }
    __syncthreads();
  }
}

extern "C" void kernel_launch(void* const* d_in, const int* in_sizes, int n_in,
                              void* d_out, int out_size, void* d_ws, size_t ws_size,
                              hipStream_t stream) {
  const float* X     = (const float*)d_in[0];
  const float* mask  = (const float*)d_in[3];
  const float* Wq    = (const float*)d_in[4];
  const float* bq    = (const float*)d_in[5];
  const float* Wk    = (const float*)d_in[6];
  const float* bk    = (const float*)d_in[7];
  const float* Wv    = (const float*)d_in[8];
  const float* bv    = (const float*)d_in[9];
  const float* Wo    = (const float*)d_in[10];
  const float* bo    = (const float*)d_in[11];
  const float* Wd    = (const float*)d_in[12];
  const float* bd    = (const float*)d_in[13];
  const float* lnl_g = (const float*)d_in[14];
  const float* lnl_b = (const float*)d_in[15];
  const float* lns_g = (const float*)d_in[16];
  const float* lns_b = (const float*)d_in[17];
  float* out = (float*)d_out;

  // per-batch fp32 workspace: ~67 MB total
  float* wsf = (float*)d_ws;
  float* Q  = wsf;                    // 2000*2048 = 4,096,000
  float* K  = Q  + 4096000;
  float* V  = K  + 4096000;
  float* C  = V  + 4096000;
  float* hs = C  + 4096000;           // 2000*128 = 256,000
  float* Kc = hs + 256000;            // 4*32*512 = 65,536
  float* Vc = Kc + 65536;             // 65,536

  const float scale = 0.04419417382415922f;  // 1/sqrt(512)
  const dim3 blk(256);

  for (int b = 0; b < 8; ++b) {
    const float* Xb = X + (size_t)b * SS * DMM;
    const float* mb = mask + (size_t)b * SS;
    float* outb = out + (size_t)b * SS * DMM;

    gemm_f32<<<dim3(32, 16), blk, 0, stream>>>(Xb, Wq, bq, Q, SS, 2048, 512, scale);
    gemm_f32<<<dim3(32, 16), blk, 0, stream>>>(Xb, Wk, bk, K, SS, 2048, 512, 1.f);
    gemm_f32<<<dim3(32, 16), blk, 0, stream>>>(Xb, Wv, bv, V, SS, 2048, 512, 1.f);
    gemm_f32<<<dim3(2, 16),  blk, 0, stream>>>(Xb, Wd, bd, hs, SS, 128, 512, 1.f);
    ln_row2048<<<SS, blk, 0, stream>>>(K, lnl_g, lnl_b);
    ln_row2048<<<SS, blk, 0, stream>>>(V, lnl_g, lnl_b);
    hs_softmax_f32<<<1, dim3(128, 8), 0, stream>>>(hs, mb);
    compress_f32<<<8, blk, 0, stream>>>(K, V, hs, Kc, Vc);
    ln_comp_f32<<<32, blk, 0, stream>>>(Kc, lns_g, lns_b);
    ln_comp_f32<<<32, blk, 0, stream>>>(Vc, lns_g, lns_b);
    attn_f32<<<HHN * GGN, blk, 0, stream>>>(Q, K, V, Kc, Vc, mb, C);
    gemm_f32<<<dim3(8, 16), blk, 0, stream>>>(C, Wo, bo, outb, SS, 512, 2048, 1.f);
  }
}

// Round 6
// 2964.910 us; speedup vs baseline: 5.5316x; 5.5316x over previous
//
#include <hip/hip_runtime.h>
#include <math.h>

#define BB 8
#define SS 2000
#define DMM 512
#define HHN 4
#define DKK 512
#define HDK 2048
#define NLL 32
#define HNL 128
#define GGN 200
#define WSZ 10
#define TTN 20
#define EXTT 5
#define MMR (BB*SS)   // 16000

typedef unsigned short bf16_t;

__device__ __forceinline__ float bf2f(bf16_t u) {
  union { unsigned u; float f; } x; x.u = ((unsigned)u) << 16; return x.f;
}
__device__ __forceinline__ bf16_t f2bf(float f) {
  union { float f; unsigned u; } x; x.f = f;
  unsigned r = x.u + 0x7FFFu + ((x.u >> 16) & 1u);
  return (bf16_t)(r >> 16);
}

// ---------------- block reduction helper (256 threads) ----------------
__device__ __forceinline__ float block_sum256(float v, float* sh) {
  #pragma unroll
  for (int off = 32; off > 0; off >>= 1) v += __shfl_down(v, off);
  if ((threadIdx.x & 63) == 0) sh[threadIdx.x >> 6] = v;
  __syncthreads();
  float t = sh[0] + sh[1] + sh[2] + sh[3];
  __syncthreads();
  return t;
}

// ---------------- GEMM: C = (A[M,K] @ W[K,N] + bias)*alpha ----------------
// W, bias fp32. A fp32 or bf16. Out fp32 or bf16. BM=128 BN=64 BK=16.
template <typename TA, typename TO>
__global__ __launch_bounds__(256)
void gemm_t(const TA* __restrict__ A, const float* __restrict__ W,
            const float* __restrict__ bias, TO* __restrict__ Cout,
            int M, int N, int K, float alpha) {
  const int BM = 128, BN = 64, BK = 16;
  __shared__ float As[BK][BM];
  __shared__ float Ws[BK][BN];
  int bm = blockIdx.y * BM, bn = blockIdx.x * BN;
  int tid = threadIdx.x;
  int tc = tid & 15, tr = tid >> 4;
  float acc[8][4];
  #pragma unroll
  for (int i = 0; i < 8; ++i)
    #pragma unroll
    for (int j = 0; j < 4; ++j) acc[i][j] = 0.f;

  for (int k0 = 0; k0 < K; k0 += BK) {
    #pragma unroll
    for (int i = tid; i < BM * BK / 4; i += 256) {
      int r = i >> 2;
      int c4 = (i & 3) << 2;
      float vx, vy, vz, vw;
      if constexpr (sizeof(TA) == 2) {
        ushort4 raw = *(const ushort4*)&A[(size_t)(bm + r) * K + k0 + c4];
        vx = bf2f(raw.x); vy = bf2f(raw.y); vz = bf2f(raw.z); vw = bf2f(raw.w);
      } else {
        float4 v = *(const float4*)&A[(size_t)(bm + r) * K + k0 + c4];
        vx = v.x; vy = v.y; vz = v.z; vw = v.w;
      }
      As[c4 + 0][r] = vx; As[c4 + 1][r] = vy;
      As[c4 + 2][r] = vz; As[c4 + 3][r] = vw;
    }
    {
      int r = tid >> 4;
      int c4 = (tid & 15) << 2;
      *(float4*)&Ws[r][c4] = *(const float4*)&W[(size_t)(k0 + r) * N + bn + c4];
    }
    __syncthreads();
    #pragma unroll
    for (int kk = 0; kk < BK; ++kk) {
      float a[8], w[4];
      *(float4*)&a[0] = *(const float4*)&As[kk][tr * 8];
      *(float4*)&a[4] = *(const float4*)&As[kk][tr * 8 + 4];
      *(float4*)&w[0] = *(const float4*)&Ws[kk][tc * 4];
      #pragma unroll
      for (int i = 0; i < 8; ++i)
        #pragma unroll
        for (int j = 0; j < 4; ++j) acc[i][j] = fmaf(a[i], w[j], acc[i][j]);
    }
    __syncthreads();
  }
  int c = bn + tc * 4;
  float4 bv = *(const float4*)&bias[c];
  #pragma unroll
  for (int i = 0; i < 8; ++i) {
    int r = bm + tr * 8 + i;
    float o0 = (acc[i][0] + bv.x) * alpha;
    float o1 = (acc[i][1] + bv.y) * alpha;
    float o2 = (acc[i][2] + bv.z) * alpha;
    float o3 = (acc[i][3] + bv.w) * alpha;
    if constexpr (sizeof(TO) == 2) {
      ushort4 o;
      o.x = f2bf(o0); o.y = f2bf(o1); o.z = f2bf(o2); o.w = f2bf(o3);
      *(ushort4*)&Cout[(size_t)r * N + c] = o;
    } else {
      float4 o; o.x = o0; o.y = o1; o.z = o2; o.w = o3;
      *(float4*)&Cout[(size_t)r * N + c] = o;
    }
  }
}

// ---------------- LayerNorm over bf16 rows of 2048 (in place) ---------------
__global__ __launch_bounds__(256)
void ln2048_bf16(bf16_t* __restrict__ Y, const float* __restrict__ gam,
                 const float* __restrict__ bet) {
  __shared__ float sh[4];
  bf16_t* y = Y + (size_t)blockIdx.x * HDK;
  int t = threadIdx.x;
  ushort4 ra = *(const ushort4*)&y[t * 8];
  ushort4 rb = *(const ushort4*)&y[t * 8 + 4];
  float v[8];
  v[0] = bf2f(ra.x); v[1] = bf2f(ra.y); v[2] = bf2f(ra.z); v[3] = bf2f(ra.w);
  v[4] = bf2f(rb.x); v[5] = bf2f(rb.y); v[6] = bf2f(rb.z); v[7] = bf2f(rb.w);
  float s = 0.f;
  #pragma unroll
  for (int j = 0; j < 8; ++j) s += v[j];
  s = block_sum256(s, sh);
  float mean = s * (1.f / 2048.f);
  float ss = 0.f;
  #pragma unroll
  for (int j = 0; j < 8; ++j) { float d = v[j] - mean; ss = fmaf(d, d, ss); }
  ss = block_sum256(ss, sh);
  float rstd = rsqrtf(ss * (1.f / 2048.f) + 1e-5f);
  float gg[8], bb[8];
  *(float4*)&gg[0] = *(const float4*)&gam[t * 8];
  *(float4*)&gg[4] = *(const float4*)&gam[t * 8 + 4];
  *(float4*)&bb[0] = *(const float4*)&bet[t * 8];
  *(float4*)&bb[4] = *(const float4*)&bet[t * 8 + 4];
  ushort4 oa, ob;
  oa.x = f2bf((v[0] - mean) * rstd * gg[0] + bb[0]);
  oa.y = f2bf((v[1] - mean) * rstd * gg[1] + bb[1]);
  oa.z = f2bf((v[2] - mean) * rstd * gg[2] + bb[2]);
  oa.w = f2bf((v[3] - mean) * rstd * gg[3] + bb[3]);
  ob.x = f2bf((v[4] - mean) * rstd * gg[4] + bb[4]);
  ob.y = f2bf((v[5] - mean) * rstd * gg[5] + bb[5]);
  ob.z = f2bf((v[6] - mean) * rstd * gg[6] + bb[6]);
  ob.w = f2bf((v[7] - mean) * rstd * gg[7] + bb[7]);
  *(ushort4*)&y[t * 8] = oa;
  *(ushort4*)&y[t * 8 + 4] = ob;
}

// ---------------- softmax over s of hs[b][s][128], parallel cols ------------
// grid = BB*8 blocks; block 256 = 16 cols x 16 s-stripes
__global__ __launch_bounds__(256)
void hs_softmax_par(float* __restrict__ hs, const float* __restrict__ mask) {
  int b = blockIdx.x >> 3, cc = blockIdx.x & 7;
  int ci = threadIdx.x & 15, ys = threadIdx.x >> 4;
  int c = cc * 16 + ci;
  __shared__ float red[16][17];
  float mx = -INFINITY;
  for (int s = ys; s < SS; s += 16) {
    float m = mask[(size_t)b * SS + s];
    float v = (m != 0.f) ? hs[((size_t)b * SS + s) * HNL + c] : -INFINITY;
    mx = fmaxf(mx, v);
  }
  red[ys][ci] = mx; __syncthreads();
  mx = red[0][ci];
  #pragma unroll
  for (int i = 1; i < 16; ++i) mx = fmaxf(mx, red[i][ci]);
  __syncthreads();
  float sum = 0.f;
  for (int s = ys; s < SS; s += 16) {
    float m = mask[(size_t)b * SS + s];
    if (m != 0.f) sum += expf(hs[((size_t)b * SS + s) * HNL + c] - mx);
  }
  red[ys][ci] = sum; __syncthreads();
  sum = 0.f;
  #pragma unroll
  for (int i = 0; i < 16; ++i) sum += red[i][ci];
  float inv = 1.f / sum;
  for (int s = ys; s < SS; s += 16) {
    size_t idx = ((size_t)b * SS + s) * HNL + c;
    float m = mask[(size_t)b * SS + s];
    hs[idx] = (m != 0.f) ? expf(hs[idx] - mx) * inv : 0.f;
  }
}

// ---------------- compression partials: atomicAdd into zeroed Kc/Vc ---------
// grid = b(8) x h(4) x dchunk(2) x schunk(8) = 512 blocks; s-range 250 each
__global__ __launch_bounds__(256)
void compress_atomic(const bf16_t* __restrict__ Kf, const bf16_t* __restrict__ Vf,
                     const float* __restrict__ hs, float* __restrict__ Kc,
                     float* __restrict__ Vc) {
  int sch = blockIdx.x & 7;
  int dchunk = (blockIdx.x >> 3) & 1;
  int h = (blockIdx.x >> 4) & 3;
  int b = blockIdx.x >> 6;
  int d = dchunk * 256 + threadIdx.x;
  float ak[NLL], av[NLL];
  #pragma unroll
  for (int l = 0; l < NLL; ++l) { ak[l] = 0.f; av[l] = 0.f; }
  __shared__ float hsh[10][32];
  int sbeg = sch * 250;
  for (int s0 = sbeg; s0 < sbeg + 250; s0 += 10) {
    for (int i = threadIdx.x; i < 320; i += 256) {
      int si = i >> 5, l = i & 31;
      hsh[si][l] = hs[((size_t)b * SS + s0 + si) * HNL + h * NLL + l];
    }
    __syncthreads();
    #pragma unroll
    for (int si = 0; si < 10; ++si) {
      float kv = bf2f(Kf[((size_t)b * SS + s0 + si) * HDK + h * DKK + d]);
      float vv = bf2f(Vf[((size_t)b * SS + s0 + si) * HDK + h * DKK + d]);
      #pragma unroll
      for (int l = 0; l < NLL; ++l) {
        float hw = hsh[si][l];
        ak[l] = fmaf(hw, kv, ak[l]);
        av[l] = fmaf(hw, vv, av[l]);
      }
    }
    __syncthreads();
  }
  size_t obase = ((size_t)b * 4 + h) * NLL * DKK + d;
  #pragma unroll
  for (int l = 0; l < NLL; ++l) {
    atomicAdd(&Kc[obase + (size_t)l * DKK], ak[l]);
    atomicAdd(&Vc[obase + (size_t)l * DKK], av[l]);
  }
}

// ---------------- LN over f=h*512+d for row (b,l) of Kc/Vc ------------------
__global__ __launch_bounds__(256)
void ln_comp(float* __restrict__ Y, const float* __restrict__ gam,
             const float* __restrict__ bet) {
  __shared__ float sh[4];
  int b = blockIdx.x >> 5, l = blockIdx.x & 31;
  size_t base = (size_t)b * 65536 + (size_t)l * 512;
  float v[8]; float s = 0.f;
  #pragma unroll
  for (int j = 0; j < 8; ++j) {
    int f = threadIdx.x + 256 * j;
    int hh = f >> 9, dd = f & 511;
    v[j] = Y[base + (size_t)hh * 16384 + dd];
    s += v[j];
  }
  s = block_sum256(s, sh);
  float mean = s * (1.f / 2048.f);
  float ss = 0.f;
  #pragma unroll
  for (int j = 0; j < 8; ++j) { float d = v[j] - mean; ss = fmaf(d, d, ss); }
  ss = block_sum256(ss, sh);
  float rstd = rsqrtf(ss * (1.f / 2048.f) + 1e-5f);
  #pragma unroll
  for (int j = 0; j < 8; ++j) {
    int f = threadIdx.x + 256 * j;
    int hh = f >> 9, dd = f & 511;
    Y[base + (size_t)hh * 16384 + dd] = (v[j] - mean) * rstd * gam[f] + bet[f];
  }
}

// ---------------- fused attention per (b,h,g) -------------------------------
// Cf aliases Qf: block (b,h,g) reads only its own Q slice (score phase) and
// writes only the same C slice (output phase) — disjoint across blocks.
__global__ __launch_bounds__(256)
void attn_bf16(const bf16_t* __restrict__ Qf, const bf16_t* __restrict__ Kf,
               const bf16_t* __restrict__ Vf, const float* __restrict__ Kc,
               const float* __restrict__ Vc, const float* __restrict__ mask,
               bf16_t* __restrict__ Cf) {
  int g = blockIdx.x % GGN;
  int bh = blockIdx.x / GGN;
  int h = bh & 3, b = bh >> 2;
  __shared__ float Qh[WSZ][260];
  __shared__ float KVh[TTN][260];
  __shared__ float sc[WSZ][64];   // 52 used
  __shared__ float colvalid[TTN];
  int tid = threadIdx.x;
  if (tid < TTN) {
    int j = g * WSZ + tid - EXTT;
    colvalid[tid] = (j >= 0 && j < SS && mask[(size_t)b * SS + j] != 0.f) ? 1.f : 0.f;
  }
  float accC0 = 0.f, accC1 = 0.f, accW = 0.f;
  for (int dh = 0; dh < 2; ++dh) {
    for (int i = tid; i < WSZ * 64; i += 256) {
      int w = i >> 6, d4 = (i & 63) << 2;
      ushort4 raw = *(const ushort4*)
          &Qf[((size_t)b * SS + g * WSZ + w) * HDK + h * DKK + dh * 256 + d4];
      Qh[w][d4 + 0] = bf2f(raw.x); Qh[w][d4 + 1] = bf2f(raw.y);
      Qh[w][d4 + 2] = bf2f(raw.z); Qh[w][d4 + 3] = bf2f(raw.w);
    }
    for (int i = tid; i < TTN * 64; i += 256) {
      int t = i >> 6, d4 = (i & 63) << 2;
      int j = g * WSZ + t - EXTT;
      if (j >= 0 && j < SS) {
        ushort4 raw = *(const ushort4*)
            &Kf[((size_t)j * BB / BB + (size_t)b * SS + j - j) * 0 +
                ((size_t)b * SS + j) * HDK + h * DKK + dh * 256 + d4];
        KVh[t][d4 + 0] = bf2f(raw.x); KVh[t][d4 + 1] = bf2f(raw.y);
        KVh[t][d4 + 2] = bf2f(raw.z); KVh[t][d4 + 3] = bf2f(raw.w);
      } else {
        KVh[t][d4 + 0] = 0.f; KVh[t][d4 + 1] = 0.f;
        KVh[t][d4 + 2] = 0.f; KVh[t][d4 + 3] = 0.f;
      }
    }
    __syncthreads();
    {
      int w = tid >> 5, c = tid & 31;
      const float* kp = Kc + (((size_t)b * 4 + h) * NLL + c) * DKK + dh * 256;
      const float* qp = &Qh[w][0];
      float a = 0.f;
      #pragma unroll 8
      for (int d = 0; d < 256; ++d) a = fmaf(qp[d], kp[d], a);
      accC0 += a;
    }
    if (tid < 64) {
      int w = 8 + (tid >> 5), c = tid & 31;
      const float* kp = Kc + (((size_t)b * 4 + h) * NLL + c) * DKK + dh * 256;
      const float* qp = &Qh[w][0];
      float a = 0.f;
      #pragma unroll 8
      for (int d = 0; d < 256; ++d) a = fmaf(qp[d], kp[d], a);
      accC1 += a;
    }
    if (tid < 200) {
      int w = tid / 20, t = tid % 20;
      const float* kp = &KVh[t][0];
      const float* qp = &Qh[w][0];
      float a = 0.f;
      #pragma unroll 8
      for (int d = 0; d < 256; ++d) a = fmaf(qp[d], kp[d], a);
      accW += a;
    }
    __syncthreads();
  }
  { int w = tid >> 5, c = tid & 31; sc[w][c] = accC0; }
  if (tid < 64) { int w = 8 + (tid >> 5), c = tid & 31; sc[w][c] = accC1; }
  if (tid < 200) {
    int w = tid / 20, t = tid % 20;
    sc[w][NLL + t] = (colvalid[t] != 0.f) ? accW : -INFINITY;
  }
  __syncthreads();
  if (tid < WSZ) {
    float mx = -INFINITY;
    for (int c = 0; c < 52; ++c) mx = fmaxf(mx, sc[tid][c]);
    float sum = 0.f;
    for (int c = 0; c < 52; ++c) { float e = expf(sc[tid][c] - mx); sc[tid][c] = e; sum += e; }
    float qm = mask[(size_t)b * SS + g * WSZ + tid];
    float inv = (qm != 0.f) ? 1.f / sum : 0.f;
    for (int c = 0; c < 52; ++c) sc[tid][c] *= inv;
  }
  __syncthreads();
  for (int dh = 0; dh < 2; ++dh) {
    for (int i = tid; i < TTN * 64; i += 256) {
      int t = i >> 6, d4 = (i & 63) << 2;
      int j = g * WSZ + t - EXTT;
      if (j >= 0 && j < SS) {
        ushort4 raw = *(const ushort4*)
            &Vf[((size_t)b * SS + j) * HDK + h * DKK + dh * 256 + d4];
        KVh[t][d4 + 0] = bf2f(raw.x); KVh[t][d4 + 1] = bf2f(raw.y);
        KVh[t][d4 + 2] = bf2f(raw.z); KVh[t][d4 + 3] = bf2f(raw.w);
      } else {
        KVh[t][d4 + 0] = 0.f; KVh[t][d4 + 1] = 0.f;
        KVh[t][d4 + 2] = 0.f; KVh[t][d4 + 3] = 0.f;
      }
    }
    __syncthreads();
    int d = tid;
    const float* vcb = Vc + ((size_t)b * 4 + h) * NLL * DKK + dh * 256 + d;
    for (int w = 0; w < WSZ; ++w) {
      float acc = 0.f;
      #pragma unroll 8
      for (int l = 0; l < NLL; ++l) acc = fmaf(sc[w][l], vcb[(size_t)l * DKK], acc);
      #pragma unroll
      for (int t = 0; t < TTN; ++t) acc = fmaf(sc[w][NLL + t], KVh[t][d], acc);
      Cf[((size_t)b * SS + g * WSZ + w) * HDK + h * DKK + dh * 256 + d] = f2bf(acc);
    }
    __syncthreads();
  }
}

extern "C" void kernel_launch(void* const* d_in, const int* in_sizes, int n_in,
                              void* d_out, int out_size, void* d_ws, size_t ws_size,
                              hipStream_t stream) {
  const float* X     = (const float*)d_in[0];
  const float* mask  = (const float*)d_in[3];
  const float* Wq    = (const float*)d_in[4];
  const float* bq    = (const float*)d_in[5];
  const float* Wk    = (const float*)d_in[6];
  const float* bk    = (const float*)d_in[7];
  const float* Wv    = (const float*)d_in[8];
  const float* bv    = (const float*)d_in[9];
  const float* Wo    = (const float*)d_in[10];
  const float* bo    = (const float*)d_in[11];
  const float* Wd    = (const float*)d_in[12];
  const float* bd    = (const float*)d_in[13];
  const float* lnl_g = (const float*)d_in[14];
  const float* lnl_b = (const float*)d_in[15];
  const float* lns_g = (const float*)d_in[16];
  const float* lns_b = (const float*)d_in[17];
  float* out = (float*)d_out;

  // workspace carve (bytes): total ~209 MB (proven safe in R2-R4)
  char* ws = (char*)d_ws;
  bf16_t* Q  = (bf16_t*)(ws);                 // 65,536,000 B
  bf16_t* K  = (bf16_t*)(ws + 65536000);      // 65,536,000 B
  bf16_t* V  = (bf16_t*)(ws + 131072000);     // 65,536,000 B
  float*  hs = (float*) (ws + 196608000);     // 8,192,000 B
  float*  Kc = (float*) (ws + 204800000);     // 2,097,152 B
  float*  Vc = (float*) (ws + 206897152);     // 2,097,152 B
  bf16_t* C  = Q;                             // alias (see attn_bf16 note)

  const float scale = 0.04419417382415922f;  // 1/sqrt(512)
  const dim3 blk(256);

  // projections (full batch, M=16000)
  gemm_t<float, bf16_t><<<dim3(32, 125), blk, 0, stream>>>(X, Wq, bq, Q, MMR, 2048, 512, scale);
  gemm_t<float, bf16_t><<<dim3(32, 125), blk, 0, stream>>>(X, Wk, bk, K, MMR, 2048, 512, 1.f);
  gemm_t<float, bf16_t><<<dim3(32, 125), blk, 0, stream>>>(X, Wv, bv, V, MMR, 2048, 512, 1.f);
  gemm_t<float, float ><<<dim3(2, 125),  blk, 0, stream>>>(X, Wd, bd, hs, MMR, 128, 512, 1.f);
  // LN on K,V rows
  ln2048_bf16<<<MMR, blk, 0, stream>>>(K, lnl_g, lnl_b);
  ln2048_bf16<<<MMR, blk, 0, stream>>>(V, lnl_g, lnl_b);
  // hs softmax (parallel over columns)
  hs_softmax_par<<<BB * 8, blk, 0, stream>>>(hs, mask);
  // landmark compression: zero Kc/Vc then atomic partials over s-chunks
  hipMemsetAsync(ws + 204800000, 0, 4194304, stream);
  compress_atomic<<<512, blk, 0, stream>>>(K, V, hs, Kc, Vc);
  ln_comp<<<BB * NLL, blk, 0, stream>>>(Kc, lns_g, lns_b);
  ln_comp<<<BB * NLL, blk, 0, stream>>>(Vc, lns_g, lns_b);
  // fused attention (writes C = alias of Q)
  attn_bf16<<<BB * HHN * GGN, blk, 0, stream>>>(Q, K, V, Kc, Vc, mask, C);
  // output projection -> fp32 out
  gemm_t<bf16_t, float><<<dim3(8, 125), blk, 0, stream>>>(C, Wo, bo, out, MMR, 512, 2048, 1.f);
}

// Round 7
// 1468.603 us; speedup vs baseline: 11.1676x; 2.0189x over previous
//
#include <hip/hip_runtime.h>
#include <math.h>

#define BB 8
#define SS 2000
#define DMM 512
#define HHN 4
#define DKK 512
#define HDK 2048
#define NLL 32
#define HNL 128
#define GGN 200
#define WSZ 10
#define TTN 20
#define EXTT 5
#define MMR (BB*SS)   // 16000

typedef unsigned short bf16_t;
typedef __attribute__((ext_vector_type(8))) short short8;
typedef __attribute__((ext_vector_type(4))) float floatx4;

__device__ __forceinline__ float bf2f(bf16_t u) {
  union { unsigned u; float f; } x; x.u = ((unsigned)u) << 16; return x.f;
}
__device__ __forceinline__ bf16_t f2bf(float f) {
  union { float f; unsigned u; } x; x.f = f;
  unsigned r = x.u + 0x7FFFu + ((x.u >> 16) & 1u);
  return (bf16_t)(r >> 16);
}

// ---------------- block reduction helper (256 threads) ----------------
__device__ __forceinline__ float block_sum256(float v, float* sh) {
  #pragma unroll
  for (int off = 32; off > 0; off >>= 1) v += __shfl_down(v, off);
  if ((threadIdx.x & 63) == 0) sh[threadIdx.x >> 6] = v;
  __syncthreads();
  float t = sh[0] + sh[1] + sh[2] + sh[3];
  __syncthreads();
  return t;
}

// ---------------- weight transpose fp32 -> bf16 B^T -------------------------
// Wt[n][k] = W[k][n]; K,N multiples of 64. grid (N/64, K/64), 256 thr.
__global__ __launch_bounds__(256)
void transpose_w(const float* __restrict__ W, bf16_t* __restrict__ Wt,
                 int K, int N) {
  __shared__ float Ts[64][65];
  int n0 = blockIdx.x * 64, k0 = blockIdx.y * 64;
  int tid = threadIdx.x;
  #pragma unroll
  for (int i = 0; i < 16; ++i) {
    int e = i * 256 + tid;
    int r = e >> 6, c = e & 63;
    Ts[r][c] = W[(size_t)(k0 + r) * N + n0 + c];
  }
  __syncthreads();
  #pragma unroll
  for (int i = 0; i < 16; ++i) {
    int e = i * 256 + tid;
    int r = e >> 6, c = e & 63;
    Wt[(size_t)(n0 + r) * K + k0 + c] = f2bf(Ts[c][r]);
  }
}

// ---------------- MFMA GEMM: Out = (A[M,K] @ Bt[N,K]^T + bias)*alpha --------
// A: fp32 (converted in staging) or bf16. Bt: bf16 row-major [N][K].
// 128x128 tile, BK=32, 4 waves, 4x4 mfma_f32_16x16x32_bf16 per wave.
// LDS XOR swizzle (chunk ^ row&3) for conflict-free b128 access.
// Requires M%128==0, N%128==0, K%32==0.
template <typename TA, typename TO>
__global__ __launch_bounds__(256)
void gemm_mfma(const TA* __restrict__ A, const bf16_t* __restrict__ Bt,
               const float* __restrict__ bias, TO* __restrict__ Cout,
               int M, int N, int K, float alpha) {
  __shared__ bf16_t As[128 * 32];
  __shared__ bf16_t Bs[128 * 32];
  int tid = threadIdx.x;
  int wave = tid >> 6, lane = tid & 63;
  int wr = wave >> 1, wc = wave & 1;
  int quad = lane >> 4, ml = lane & 15;
  int bm = blockIdx.y * 128, bn = blockIdx.x * 128;

  floatx4 acc[4][4];
  #pragma unroll
  for (int i = 0; i < 4; ++i)
    #pragma unroll
    for (int j = 0; j < 4; ++j)
      #pragma unroll
      for (int r = 0; r < 4; ++r) acc[i][j][r] = 0.f;

  for (int k0 = 0; k0 < K; k0 += 32) {
    // stage A and Bt tiles: idx in [0,512): row=idx>>2, 8-elem chunk=idx&3
    #pragma unroll
    for (int p = 0; p < 2; ++p) {
      int idx = p * 256 + tid;
      int row = idx >> 2, ch = idx & 3;
      int sw = ch ^ (row & 3);
      // A tile
      if constexpr (sizeof(TA) == 4) {
        float4 a0 = *(const float4*)&A[(size_t)(bm + row) * K + k0 + ch * 8];
        float4 a1 = *(const float4*)&A[(size_t)(bm + row) * K + k0 + ch * 8 + 4];
        ushort4 u0, u1;
        u0.x = f2bf(a0.x); u0.y = f2bf(a0.y); u0.z = f2bf(a0.z); u0.w = f2bf(a0.w);
        u1.x = f2bf(a1.x); u1.y = f2bf(a1.y); u1.z = f2bf(a1.z); u1.w = f2bf(a1.w);
        *(ushort4*)&As[row * 32 + sw * 8]     = u0;
        *(ushort4*)&As[row * 32 + sw * 8 + 4] = u1;
      } else {
        uint4 raw = *(const uint4*)&A[(size_t)(bm + row) * K + k0 + ch * 8];
        *(uint4*)&As[row * 32 + sw * 8] = raw;
      }
      // B tile (Bt rows are k-contiguous)
      uint4 braw = *(const uint4*)&Bt[(size_t)(bn + row) * K + k0 + ch * 8];
      *(uint4*)&Bs[row * 32 + sw * 8] = braw;
    }
    __syncthreads();
    short8 af[4], bfr[4];
    #pragma unroll
    for (int i = 0; i < 4; ++i) {
      int row = wr * 64 + i * 16 + ml;
      int sw = quad ^ (row & 3);
      af[i] = *(const short8*)&As[row * 32 + sw * 8];
    }
    #pragma unroll
    for (int j = 0; j < 4; ++j) {
      int row = wc * 64 + j * 16 + ml;
      int sw = quad ^ (row & 3);
      bfr[j] = *(const short8*)&Bs[row * 32 + sw * 8];
    }
    #pragma unroll
    for (int i = 0; i < 4; ++i)
      #pragma unroll
      for (int j = 0; j < 4; ++j)
        acc[i][j] = __builtin_amdgcn_mfma_f32_16x16x32_bf16(af[i], bfr[j], acc[i][j], 0, 0, 0);
    __syncthreads();
  }
  // epilogue: D row = quad*4+r, col = ml within each 16x16 block
  #pragma unroll
  for (int i = 0; i < 4; ++i) {
    int row0 = bm + wr * 64 + i * 16 + quad * 4;
    #pragma unroll
    for (int j = 0; j < 4; ++j) {
      int col = bn + wc * 64 + j * 16 + ml;
      float bv = bias[col];
      #pragma unroll
      for (int r = 0; r < 4; ++r) {
        float o = (acc[i][j][r] + bv) * alpha;
        if constexpr (sizeof(TO) == 2)
          Cout[(size_t)(row0 + r) * N + col] = f2bf(o);
        else
          Cout[(size_t)(row0 + r) * N + col] = o;
      }
    }
  }
}

// ---------------- LayerNorm over bf16 rows of 2048 (in place) ---------------
__global__ __launch_bounds__(256)
void ln2048_bf16(bf16_t* __restrict__ Y, const float* __restrict__ gam,
                 const float* __restrict__ bet) {
  __shared__ float sh[4];
  bf16_t* y = Y + (size_t)blockIdx.x * HDK;
  int t = threadIdx.x;
  ushort4 ra = *(const ushort4*)&y[t * 8];
  ushort4 rb = *(const ushort4*)&y[t * 8 + 4];
  float v[8];
  v[0] = bf2f(ra.x); v[1] = bf2f(ra.y); v[2] = bf2f(ra.z); v[3] = bf2f(ra.w);
  v[4] = bf2f(rb.x); v[5] = bf2f(rb.y); v[6] = bf2f(rb.z); v[7] = bf2f(rb.w);
  float s = 0.f;
  #pragma unroll
  for (int j = 0; j < 8; ++j) s += v[j];
  s = block_sum256(s, sh);
  float mean = s * (1.f / 2048.f);
  float ss = 0.f;
  #pragma unroll
  for (int j = 0; j < 8; ++j) { float d = v[j] - mean; ss = fmaf(d, d, ss); }
  ss = block_sum256(ss, sh);
  float rstd = rsqrtf(ss * (1.f / 2048.f) + 1e-5f);
  float gg[8], bb[8];
  *(float4*)&gg[0] = *(const float4*)&gam[t * 8];
  *(float4*)&gg[4] = *(const float4*)&gam[t * 8 + 4];
  *(float4*)&bb[0] = *(const float4*)&bet[t * 8];
  *(float4*)&bb[4] = *(const float4*)&bet[t * 8 + 4];
  ushort4 oa, ob;
  oa.x = f2bf((v[0] - mean) * rstd * gg[0] + bb[0]);
  oa.y = f2bf((v[1] - mean) * rstd * gg[1] + bb[1]);
  oa.z = f2bf((v[2] - mean) * rstd * gg[2] + bb[2]);
  oa.w = f2bf((v[3] - mean) * rstd * gg[3] + bb[3]);
  ob.x = f2bf((v[4] - mean) * rstd * gg[4] + bb[4]);
  ob.y = f2bf((v[5] - mean) * rstd * gg[5] + bb[5]);
  ob.z = f2bf((v[6] - mean) * rstd * gg[6] + bb[6]);
  ob.w = f2bf((v[7] - mean) * rstd * gg[7] + bb[7]);
  *(ushort4*)&y[t * 8] = oa;
  *(ushort4*)&y[t * 8 + 4] = ob;
}

// ---------------- softmax over s of hs[b][s][128], parallel cols ------------
__global__ __launch_bounds__(256)
void hs_softmax_par(float* __restrict__ hs, const float* __restrict__ mask) {
  int b = blockIdx.x >> 3, cc = blockIdx.x & 7;
  int ci = threadIdx.x & 15, ys = threadIdx.x >> 4;
  int c = cc * 16 + ci;
  __shared__ float red[16][17];
  float mx = -INFINITY;
  for (int s = ys; s < SS; s += 16) {
    float m = mask[(size_t)b * SS + s];
    float v = (m != 0.f) ? hs[((size_t)b * SS + s) * HNL + c] : -INFINITY;
    mx = fmaxf(mx, v);
  }
  red[ys][ci] = mx; __syncthreads();
  mx = red[0][ci];
  #pragma unroll
  for (int i = 1; i < 16; ++i) mx = fmaxf(mx, red[i][ci]);
  __syncthreads();
  float sum = 0.f;
  for (int s = ys; s < SS; s += 16) {
    float m = mask[(size_t)b * SS + s];
    if (m != 0.f) sum += expf(hs[((size_t)b * SS + s) * HNL + c] - mx);
  }
  red[ys][ci] = sum; __syncthreads();
  sum = 0.f;
  #pragma unroll
  for (int i = 0; i < 16; ++i) sum += red[i][ci];
  float inv = 1.f / sum;
  for (int s = ys; s < SS; s += 16) {
    size_t idx = ((size_t)b * SS + s) * HNL + c;
    float m = mask[(size_t)b * SS + s];
    hs[idx] = (m != 0.f) ? expf(hs[idx] - mx) * inv : 0.f;
  }
}

// ---------------- compression partials: atomicAdd into zeroed Kc/Vc ---------
__global__ __launch_bounds__(256)
void compress_atomic(const bf16_t* __restrict__ Kf, const bf16_t* __restrict__ Vf,
                     const float* __restrict__ hs, float* __restrict__ Kc,
                     float* __restrict__ Vc) {
  int sch = blockIdx.x & 7;
  int dchunk = (blockIdx.x >> 3) & 1;
  int h = (blockIdx.x >> 4) & 3;
  int b = blockIdx.x >> 6;
  int d = dchunk * 256 + threadIdx.x;
  float ak[NLL], av[NLL];
  #pragma unroll
  for (int l = 0; l < NLL; ++l) { ak[l] = 0.f; av[l] = 0.f; }
  __shared__ float hsh[10][32];
  int sbeg = sch * 250;
  for (int s0 = sbeg; s0 < sbeg + 250; s0 += 10) {
    for (int i = threadIdx.x; i < 320; i += 256) {
      int si = i >> 5, l = i & 31;
      hsh[si][l] = hs[((size_t)b * SS + s0 + si) * HNL + h * NLL + l];
    }
    __syncthreads();
    #pragma unroll
    for (int si = 0; si < 10; ++si) {
      float kv = bf2f(Kf[((size_t)b * SS + s0 + si) * HDK + h * DKK + d]);
      float vv = bf2f(Vf[((size_t)b * SS + s0 + si) * HDK + h * DKK + d]);
      #pragma unroll
      for (int l = 0; l < NLL; ++l) {
        float hw = hsh[si][l];
        ak[l] = fmaf(hw, kv, ak[l]);
        av[l] = fmaf(hw, vv, av[l]);
      }
    }
    __syncthreads();
  }
  size_t obase = ((size_t)b * 4 + h) * NLL * DKK + d;
  #pragma unroll
  for (int l = 0; l < NLL; ++l) {
    atomicAdd(&Kc[obase + (size_t)l * DKK], ak[l]);
    atomicAdd(&Vc[obase + (size_t)l * DKK], av[l]);
  }
}

// ---------------- LN over f=h*512+d for row (b,l) of Kc/Vc ------------------
__global__ __launch_bounds__(256)
void ln_comp(float* __restrict__ Y, const float* __restrict__ gam,
             const float* __restrict__ bet) {
  __shared__ float sh[4];
  int b = blockIdx.x >> 5, l = blockIdx.x & 31;
  size_t base = (size_t)b * 65536 + (size_t)l * 512;
  float v[8]; float s = 0.f;
  #pragma unroll
  for (int j = 0; j < 8; ++j) {
    int f = threadIdx.x + 256 * j;
    int hh = f >> 9, dd = f & 511;
    v[j] = Y[base + (size_t)hh * 16384 + dd];
    s += v[j];
  }
  s = block_sum256(s, sh);
  float mean = s * (1.f / 2048.f);
  float ss = 0.f;
  #pragma unroll
  for (int j = 0; j < 8; ++j) { float d = v[j] - mean; ss = fmaf(d, d, ss); }
  ss = block_sum256(ss, sh);
  float rstd = rsqrtf(ss * (1.f / 2048.f) + 1e-5f);
  #pragma unroll
  for (int j = 0; j < 8; ++j) {
    int f = threadIdx.x + 256 * j;
    int hh = f >> 9, dd = f & 511;
    Y[base + (size_t)hh * 16384 + dd] = (v[j] - mean) * rstd * gam[f] + bet[f];
  }
}

// ---------------- fused attention per (b,h,g) -------------------------------
// Cf aliases Qf: block (b,h,g) reads only its own Q slice (score phase) and
// writes only the same C slice (output phase) — disjoint across blocks.
__global__ __launch_bounds__(256)
void attn_bf16(const bf16_t* __restrict__ Qf, const bf16_t* __restrict__ Kf,
               const bf16_t* __restrict__ Vf, const float* __restrict__ Kc,
               const float* __restrict__ Vc, const float* __restrict__ mask,
               bf16_t* __restrict__ Cf) {
  int g = blockIdx.x % GGN;
  int bh = blockIdx.x / GGN;
  int h = bh & 3, b = bh >> 2;
  __shared__ float Qh[WSZ][260];
  __shared__ float KVh[TTN][260];
  __shared__ float sc[WSZ][64];   // 52 used
  __shared__ float colvalid[TTN];
  int tid = threadIdx.x;
  if (tid < TTN) {
    int j = g * WSZ + tid - EXTT;
    colvalid[tid] = (j >= 0 && j < SS && mask[(size_t)b * SS + j] != 0.f) ? 1.f : 0.f;
  }
  float accC0 = 0.f, accC1 = 0.f, accW = 0.f;
  for (int dh = 0; dh < 2; ++dh) {
    for (int i = tid; i < WSZ * 64; i += 256) {
      int w = i >> 6, d4 = (i & 63) << 2;
      ushort4 raw = *(const ushort4*)
          &Qf[((size_t)b * SS + g * WSZ + w) * HDK + h * DKK + dh * 256 + d4];
      Qh[w][d4 + 0] = bf2f(raw.x); Qh[w][d4 + 1] = bf2f(raw.y);
      Qh[w][d4 + 2] = bf2f(raw.z); Qh[w][d4 + 3] = bf2f(raw.w);
    }
    for (int i = tid; i < TTN * 64; i += 256) {
      int t = i >> 6, d4 = (i & 63) << 2;
      int j = g * WSZ + t - EXTT;
      if (j >= 0 && j < SS) {
        ushort4 raw = *(const ushort4*)
            &Kf[((size_t)b * SS + j) * HDK + h * DKK + dh * 256 + d4];
        KVh[t][d4 + 0] = bf2f(raw.x); KVh[t][d4 + 1] = bf2f(raw.y);
        KVh[t][d4 + 2] = bf2f(raw.z); KVh[t][d4 + 3] = bf2f(raw.w);
      } else {
        KVh[t][d4 + 0] = 0.f; KVh[t][d4 + 1] = 0.f;
        KVh[t][d4 + 2] = 0.f; KVh[t][d4 + 3] = 0.f;
      }
    }
    __syncthreads();
    {
      int w = tid >> 5, c = tid & 31;
      const float* kp = Kc + (((size_t)b * 4 + h) * NLL + c) * DKK + dh * 256;
      const float* qp = &Qh[w][0];
      float a = 0.f;
      #pragma unroll 8
      for (int d = 0; d < 256; ++d) a = fmaf(qp[d], kp[d], a);
      accC0 += a;
    }
    if (tid < 64) {
      int w = 8 + (tid >> 5), c = tid & 31;
      const float* kp = Kc + (((size_t)b * 4 + h) * NLL + c) * DKK + dh * 256;
      const float* qp = &Qh[w][0];
      float a = 0.f;
      #pragma unroll 8
      for (int d = 0; d < 256; ++d) a = fmaf(qp[d], kp[d], a);
      accC1 += a;
    }
    if (tid < 200) {
      int w = tid / 20, t = tid % 20;
      const float* kp = &KVh[t][0];
      const float* qp = &Qh[w][0];
      float a = 0.f;
      #pragma unroll 8
      for (int d = 0; d < 256; ++d) a = fmaf(qp[d], kp[d], a);
      accW += a;
    }
    __syncthreads();
  }
  { int w = tid >> 5, c = tid & 31; sc[w][c] = accC0; }
  if (tid < 64) { int w = 8 + (tid >> 5), c = tid & 31; sc[w][c] = accC1; }
  if (tid < 200) {
    int w = tid / 20, t = tid % 20;
    sc[w][NLL + t] = (colvalid[t] != 0.f) ? accW : -INFINITY;
  }
  __syncthreads();
  if (tid < WSZ) {
    float mx = -INFINITY;
    for (int c = 0; c < 52; ++c) mx = fmaxf(mx, sc[tid][c]);
    float sum = 0.f;
    for (int c = 0; c < 52; ++c) { float e = expf(sc[tid][c] - mx); sc[tid][c] = e; sum += e; }
    float qm = mask[(size_t)b * SS + g * WSZ + tid];
    float inv = (qm != 0.f) ? 1.f / sum : 0.f;
    for (int c = 0; c < 52; ++c) sc[tid][c] *= inv;
  }
  __syncthreads();
  for (int dh = 0; dh < 2; ++dh) {
    for (int i = tid; i < TTN * 64; i += 256) {
      int t = i >> 6, d4 = (i & 63) << 2;
      int j = g * WSZ + t - EXTT;
      if (j >= 0 && j < SS) {
        ushort4 raw = *(const ushort4*)
            &Vf[((size_t)b * SS + j) * HDK + h * DKK + dh * 256 + d4];
        KVh[t][d4 + 0] = bf2f(raw.x); KVh[t][d4 + 1] = bf2f(raw.y);
        KVh[t][d4 + 2] = bf2f(raw.z); KVh[t][d4 + 3] = bf2f(raw.w);
      } else {
        KVh[t][d4 + 0] = 0.f; KVh[t][d4 + 1] = 0.f;
        KVh[t][d4 + 2] = 0.f; KVh[t][d4 + 3] = 0.f;
      }
    }
    __syncthreads();
    int d = tid;
    const float* vcb = Vc + ((size_t)b * 4 + h) * NLL * DKK + dh * 256 + d;
    for (int w = 0; w < WSZ; ++w) {
      float acc = 0.f;
      #pragma unroll 8
      for (int l = 0; l < NLL; ++l) acc = fmaf(sc[w][l], vcb[(size_t)l * DKK], acc);
      #pragma unroll
      for (int t = 0; t < TTN; ++t) acc = fmaf(sc[w][NLL + t], KVh[t][d], acc);
      Cf[((size_t)b * SS + g * WSZ + w) * HDK + h * DKK + dh * 256 + d] = f2bf(acc);
    }
    __syncthreads();
  }
}

extern "C" void kernel_launch(void* const* d_in, const int* in_sizes, int n_in,
                              void* d_out, int out_size, void* d_ws, size_t ws_size,
                              hipStream_t stream) {
  const float* X     = (const float*)d_in[0];
  const float* mask  = (const float*)d_in[3];
  const float* Wq    = (const float*)d_in[4];
  const float* bq    = (const float*)d_in[5];
  const float* Wk    = (const float*)d_in[6];
  const float* bk    = (const float*)d_in[7];
  const float* Wv    = (const float*)d_in[8];
  const float* bv    = (const float*)d_in[9];
  const float* Wo    = (const float*)d_in[10];
  const float* bo    = (const float*)d_in[11];
  const float* Wd    = (const float*)d_in[12];
  const float* bd    = (const float*)d_in[13];
  const float* lnl_g = (const float*)d_in[14];
  const float* lnl_b = (const float*)d_in[15];
  const float* lns_g = (const float*)d_in[16];
  const float* lns_b = (const float*)d_in[17];
  float* out = (float*)d_out;

  // workspace carve (bytes): total ~209 MB (proven safe R2-R6)
  char* ws = (char*)d_ws;
  bf16_t* Q   = (bf16_t*)(ws);                 // 65,536,000 B
  bf16_t* K   = (bf16_t*)(ws + 65536000);      // 65,536,000 B
  bf16_t* V   = (bf16_t*)(ws + 131072000);     // 65,536,000 B
  float*  hs  = (float*) (ws + 196608000);     // 8,192,000 B
  float*  Kc  = (float*) (ws + 204800000);     // 2,097,152 B
  float*  Vc  = (float*) (ws + 206897152);     // 2,097,152 B
  bf16_t* C   = Q;                             // alias (see attn_bf16 note)
  // transient bf16 B^T weights packed into regions that are dead at use time:
  bf16_t* Wqt = (bf16_t*)(ws + 196608000);           // 2,097,152 B (hs region)
  bf16_t* Wkt = (bf16_t*)(ws + 196608000 + 2097152); // 2,097,152 B
  bf16_t* Wvt = (bf16_t*)(ws + 196608000 + 4194304); // 2,097,152 B
  bf16_t* Wdt = (bf16_t*)(ws + 204800000);           // 131,072 B (Kc region)
  bf16_t* Wot = (bf16_t*)(ws + 65536000);            // 2,097,152 B (K region, post-attn)

  const float scale = 0.04419417382415922f;  // 1/sqrt(512)
  const dim3 blk(256);

  // 1. transpose weights to bf16 B^T (into hs/Kc regions, consumed below)
  transpose_w<<<dim3(32, 8), blk, 0, stream>>>(Wq, Wqt, 512, 2048);
  transpose_w<<<dim3(32, 8), blk, 0, stream>>>(Wk, Wkt, 512, 2048);
  transpose_w<<<dim3(32, 8), blk, 0, stream>>>(Wv, Wvt, 512, 2048);
  transpose_w<<<dim3(2, 8),  blk, 0, stream>>>(Wd, Wdt, 512, 128);
  // 2. Q/K/V projections (MFMA; A=fp32 X converted in staging)
  gemm_mfma<float, bf16_t><<<dim3(16, 125), blk, 0, stream>>>(X, Wqt, bq, Q, MMR, 2048, 512, scale);
  gemm_mfma<float, bf16_t><<<dim3(16, 125), blk, 0, stream>>>(X, Wkt, bk, K, MMR, 2048, 512, 1.f);
  gemm_mfma<float, bf16_t><<<dim3(16, 125), blk, 0, stream>>>(X, Wvt, bv, V, MMR, 2048, 512, 1.f);
  // 3. hs projection (overwrites Wqt/Wkt/Wvt region; reads Wdt in Kc region)
  gemm_mfma<float, float ><<<dim3(1, 125),  blk, 0, stream>>>(X, Wdt, bd, hs, MMR, 128, 512, 1.f);
  // 4. LN on K,V rows; hs softmax
  ln2048_bf16<<<MMR, blk, 0, stream>>>(K, lnl_g, lnl_b);
  ln2048_bf16<<<MMR, blk, 0, stream>>>(V, lnl_g, lnl_b);
  hs_softmax_par<<<BB * 8, blk, 0, stream>>>(hs, mask);
  // 5. landmark compression (memset overwrites Wdt — consumed in step 3)
  hipMemsetAsync(ws + 204800000, 0, 4194304, stream);
  compress_atomic<<<512, blk, 0, stream>>>(K, V, hs, Kc, Vc);
  ln_comp<<<BB * NLL, blk, 0, stream>>>(Kc, lns_g, lns_b);
  ln_comp<<<BB * NLL, blk, 0, stream>>>(Vc, lns_g, lns_b);
  // 6. fused attention (writes C = alias of Q)
  attn_bf16<<<BB * HHN * GGN, blk, 0, stream>>>(Q, K, V, Kc, Vc, mask, C);
  // 7. transpose Wo into dead K region, then output projection (MFMA)
  transpose_w<<<dim3(8, 32), blk, 0, stream>>>(Wo, Wot, 2048, 512);
  gemm_mfma<bf16_t, float><<<dim3(4, 125), blk, 0, stream>>>(C, Wot, bo, out, MMR, 512, 2048, 1.f);
}

// Round 9
// 897.734 us; speedup vs baseline: 18.2691x; 1.6359x over previous
//
#include <hip/hip_runtime.h>
#include <math.h>

#define BB 8
#define SS 2000
#define DMM 512
#define HHN 4
#define DKK 512
#define HDK 2048
#define NLL 32
#define HNL 128
#define GGN 200
#define WSZ 10
#define TTN 20
#define EXTT 5
#define MMR (BB*SS)   // 16000

typedef unsigned short bf16_t;
typedef __attribute__((ext_vector_type(8))) short short8;
typedef __attribute__((ext_vector_type(4))) float floatx4;

__device__ __forceinline__ float bf2f(bf16_t u) {
  union { unsigned u; float f; } x; x.u = ((unsigned)u) << 16; return x.f;
}
__device__ __forceinline__ bf16_t f2bf(float f) {
  union { float f; unsigned u; } x; x.f = f;
  unsigned r = x.u + 0x7FFFu + ((x.u >> 16) & 1u);
  return (bf16_t)(r >> 16);
}

// ---------------- block reduction helper (256 threads) ----------------
__device__ __forceinline__ float block_sum256(float v, float* sh) {
  #pragma unroll
  for (int off = 32; off > 0; off >>= 1) v += __shfl_down(v, off);
  if ((threadIdx.x & 63) == 0) sh[threadIdx.x >> 6] = v;
  __syncthreads();
  float t = sh[0] + sh[1] + sh[2] + sh[3];
  __syncthreads();
  return t;
}

// ---------------- weight transpose fp32 -> bf16 B^T -------------------------
__global__ __launch_bounds__(256)
void transpose_w(const float* __restrict__ W, bf16_t* __restrict__ Wt,
                 int K, int N) {
  __shared__ float Ts[64][65];
  int n0 = blockIdx.x * 64, k0 = blockIdx.y * 64;
  int tid = threadIdx.x;
  #pragma unroll
  for (int i = 0; i < 16; ++i) {
    int e = i * 256 + tid;
    int r = e >> 6, c = e & 63;
    Ts[r][c] = W[(size_t)(k0 + r) * N + n0 + c];
  }
  __syncthreads();
  #pragma unroll
  for (int i = 0; i < 16; ++i) {
    int e = i * 256 + tid;
    int r = e >> 6, c = e & 63;
    Wt[(size_t)(n0 + r) * K + k0 + c] = f2bf(Ts[c][r]);
  }
}

// ---------------- MFMA GEMM: Out = (A[M,K] @ Bt[N,K]^T + bias)*alpha --------
template <typename TA, typename TO>
__global__ __launch_bounds__(256)
void gemm_mfma(const TA* __restrict__ A, const bf16_t* __restrict__ Bt,
               const float* __restrict__ bias, TO* __restrict__ Cout,
               int M, int N, int K, float alpha) {
  __shared__ bf16_t As[128 * 32];
  __shared__ bf16_t Bs[128 * 32];
  int tid = threadIdx.x;
  int wave = tid >> 6, lane = tid & 63;
  int wr = wave >> 1, wc = wave & 1;
  int quad = lane >> 4, ml = lane & 15;
  int bm = blockIdx.y * 128, bn = blockIdx.x * 128;

  floatx4 acc[4][4];
  #pragma unroll
  for (int i = 0; i < 4; ++i)
    #pragma unroll
    for (int j = 0; j < 4; ++j)
      #pragma unroll
      for (int r = 0; r < 4; ++r) acc[i][j][r] = 0.f;

  for (int k0 = 0; k0 < K; k0 += 32) {
    #pragma unroll
    for (int p = 0; p < 2; ++p) {
      int idx = p * 256 + tid;
      int row = idx >> 2, ch = idx & 3;
      int sw = ch ^ (row & 3);
      if constexpr (sizeof(TA) == 4) {
        float4 a0 = *(const float4*)&A[(size_t)(bm + row) * K + k0 + ch * 8];
        float4 a1 = *(const float4*)&A[(size_t)(bm + row) * K + k0 + ch * 8 + 4];
        ushort4 u0, u1;
        u0.x = f2bf(a0.x); u0.y = f2bf(a0.y); u0.z = f2bf(a0.z); u0.w = f2bf(a0.w);
        u1.x = f2bf(a1.x); u1.y = f2bf(a1.y); u1.z = f2bf(a1.z); u1.w = f2bf(a1.w);
        *(ushort4*)&As[row * 32 + sw * 8]     = u0;
        *(ushort4*)&As[row * 32 + sw * 8 + 4] = u1;
      } else {
        uint4 raw = *(const uint4*)&A[(size_t)(bm + row) * K + k0 + ch * 8];
        *(uint4*)&As[row * 32 + sw * 8] = raw;
      }
      uint4 braw = *(const uint4*)&Bt[(size_t)(bn + row) * K + k0 + ch * 8];
      *(uint4*)&Bs[row * 32 + sw * 8] = braw;
    }
    __syncthreads();
    short8 af[4], bfr[4];
    #pragma unroll
    for (int i = 0; i < 4; ++i) {
      int row = wr * 64 + i * 16 + ml;
      int sw = quad ^ (row & 3);
      af[i] = *(const short8*)&As[row * 32 + sw * 8];
    }
    #pragma unroll
    for (int j = 0; j < 4; ++j) {
      int row = wc * 64 + j * 16 + ml;
      int sw = quad ^ (row & 3);
      bfr[j] = *(const short8*)&Bs[row * 32 + sw * 8];
    }
    #pragma unroll
    for (int i = 0; i < 4; ++i)
      #pragma unroll
      for (int j = 0; j < 4; ++j)
        acc[i][j] = __builtin_amdgcn_mfma_f32_16x16x32_bf16(af[i], bfr[j], acc[i][j], 0, 0, 0);
    __syncthreads();
  }
  #pragma unroll
  for (int i = 0; i < 4; ++i) {
    int row0 = bm + wr * 64 + i * 16 + quad * 4;
    #pragma unroll
    for (int j = 0; j < 4; ++j) {
      int col = bn + wc * 64 + j * 16 + ml;
      float bv = bias[col];
      #pragma unroll
      for (int r = 0; r < 4; ++r) {
        float o = (acc[i][j][r] + bv) * alpha;
        if constexpr (sizeof(TO) == 2)
          Cout[(size_t)(row0 + r) * N + col] = f2bf(o);
        else
          Cout[(size_t)(row0 + r) * N + col] = o;
      }
    }
  }
}

// ---------------- LayerNorm over bf16 rows of 2048 (in place) ---------------
__global__ __launch_bounds__(256)
void ln2048_bf16(bf16_t* __restrict__ Y, const float* __restrict__ gam,
                 const float* __restrict__ bet) {
  __shared__ float sh[4];
  bf16_t* y = Y + (size_t)blockIdx.x * HDK;
  int t = threadIdx.x;
  ushort4 ra = *(const ushort4*)&y[t * 8];
  ushort4 rb = *(const ushort4*)&y[t * 8 + 4];
  float v[8];
  v[0] = bf2f(ra.x); v[1] = bf2f(ra.y); v[2] = bf2f(ra.z); v[3] = bf2f(ra.w);
  v[4] = bf2f(rb.x); v[5] = bf2f(rb.y); v[6] = bf2f(rb.z); v[7] = bf2f(rb.w);
  float s = 0.f;
  #pragma unroll
  for (int j = 0; j < 8; ++j) s += v[j];
  s = block_sum256(s, sh);
  float mean = s * (1.f / 2048.f);
  float ss = 0.f;
  #pragma unroll
  for (int j = 0; j < 8; ++j) { float d = v[j] - mean; ss = fmaf(d, d, ss); }
  ss = block_sum256(ss, sh);
  float rstd = rsqrtf(ss * (1.f / 2048.f) + 1e-5f);
  float gg[8], bb[8];
  *(float4*)&gg[0] = *(const float4*)&gam[t * 8];
  *(float4*)&gg[4] = *(const float4*)&gam[t * 8 + 4];
  *(float4*)&bb[0] = *(const float4*)&bet[t * 8];
  *(float4*)&bb[4] = *(const float4*)&bet[t * 8 + 4];
  ushort4 oa, ob;
  oa.x = f2bf((v[0] - mean) * rstd * gg[0] + bb[0]);
  oa.y = f2bf((v[1] - mean) * rstd * gg[1] + bb[1]);
  oa.z = f2bf((v[2] - mean) * rstd * gg[2] + bb[2]);
  oa.w = f2bf((v[3] - mean) * rstd * gg[3] + bb[3]);
  ob.x = f2bf((v[4] - mean) * rstd * gg[4] + bb[4]);
  ob.y = f2bf((v[5] - mean) * rstd * gg[5] + bb[5]);
  ob.z = f2bf((v[6] - mean) * rstd * gg[6] + bb[6]);
  ob.w = f2bf((v[7] - mean) * rstd * gg[7] + bb[7]);
  *(ushort4*)&y[t * 8] = oa;
  *(ushort4*)&y[t * 8 + 4] = ob;
}

// ---------------- softmax over s of hs[b][s][128], parallel cols ------------
__global__ __launch_bounds__(256)
void hs_softmax_par(float* __restrict__ hs, const float* __restrict__ mask) {
  int b = blockIdx.x >> 3, cc = blockIdx.x & 7;
  int ci = threadIdx.x & 15, ys = threadIdx.x >> 4;
  int c = cc * 16 + ci;
  __shared__ float red[16][17];
  float mx = -INFINITY;
  for (int s = ys; s < SS; s += 16) {
    float m = mask[(size_t)b * SS + s];
    float v = (m != 0.f) ? hs[((size_t)b * SS + s) * HNL + c] : -INFINITY;
    mx = fmaxf(mx, v);
  }
  red[ys][ci] = mx; __syncthreads();
  mx = red[0][ci];
  #pragma unroll
  for (int i = 1; i < 16; ++i) mx = fmaxf(mx, red[i][ci]);
  __syncthreads();
  float sum = 0.f;
  for (int s = ys; s < SS; s += 16) {
    float m = mask[(size_t)b * SS + s];
    if (m != 0.f) sum += expf(hs[((size_t)b * SS + s) * HNL + c] - mx);
  }
  red[ys][ci] = sum; __syncthreads();
  sum = 0.f;
  #pragma unroll
  for (int i = 0; i < 16; ++i) sum += red[i][ci];
  float inv = 1.f / sum;
  for (int s = ys; s < SS; s += 16) {
    size_t idx = ((size_t)b * SS + s) * HNL + c;
    float m = mask[(size_t)b * SS + s];
    hs[idx] = (m != 0.f) ? expf(hs[idx] - mx) * inv : 0.f;
  }
}

// ---------------- compression partials: atomicAdd into zeroed Kc/Vc ---------
__global__ __launch_bounds__(256)
void compress_atomic(const bf16_t* __restrict__ Kf, const bf16_t* __restrict__ Vf,
                     const float* __restrict__ hs, float* __restrict__ Kc,
                     float* __restrict__ Vc) {
  int sch = blockIdx.x & 7;
  int dchunk = (blockIdx.x >> 3) & 1;
  int h = (blockIdx.x >> 4) & 3;
  int b = blockIdx.x >> 6;
  int d = dchunk * 256 + threadIdx.x;
  float ak[NLL], av[NLL];
  #pragma unroll
  for (int l = 0; l < NLL; ++l) { ak[l] = 0.f; av[l] = 0.f; }
  __shared__ float hsh[10][32];
  int sbeg = sch * 250;
  for (int s0 = sbeg; s0 < sbeg + 250; s0 += 10) {
    for (int i = threadIdx.x; i < 320; i += 256) {
      int si = i >> 5, l = i & 31;
      hsh[si][l] = hs[((size_t)b * SS + s0 + si) * HNL + h * NLL + l];
    }
    __syncthreads();
    #pragma unroll
    for (int si = 0; si < 10; ++si) {
      float kv = bf2f(Kf[((size_t)b * SS + s0 + si) * HDK + h * DKK + d]);
      float vv = bf2f(Vf[((size_t)b * SS + s0 + si) * HDK + h * DKK + d]);
      #pragma unroll
      for (int l = 0; l < NLL; ++l) {
        float hw = hsh[si][l];
        ak[l] = fmaf(hw, kv, ak[l]);
        av[l] = fmaf(hw, vv, av[l]);
      }
    }
    __syncthreads();
  }
  size_t obase = ((size_t)b * 4 + h) * NLL * DKK + d;
  #pragma unroll
  for (int l = 0; l < NLL; ++l) {
    atomicAdd(&Kc[obase + (size_t)l * DKK], ak[l]);
    atomicAdd(&Vc[obase + (size_t)l * DKK], av[l]);
  }
}

// ---------------- LN on Kc/Vc rows, bf16 output (row or transposed) ---------
// grid 256 = b(8) x l(32). transposed=0: out[((b*4+h)*32+l)*512+d]
//                          transposed=1: out[((b*4+h)*512+d)*32+l]
__global__ __launch_bounds__(256)
void ln_comp_out(const float* __restrict__ Y, const float* __restrict__ gam,
                 const float* __restrict__ bet, bf16_t* __restrict__ outp,
                 int transposed) {
  __shared__ float sh[4];
  int b = blockIdx.x >> 5, l = blockIdx.x & 31;
  size_t base = (size_t)b * 65536 + (size_t)l * 512;
  float v[8]; float s = 0.f;
  #pragma unroll
  for (int j = 0; j < 8; ++j) {
    int f = threadIdx.x + 256 * j;
    int hh = f >> 9, dd = f & 511;
    v[j] = Y[base + (size_t)hh * 16384 + dd];
    s += v[j];
  }
  s = block_sum256(s, sh);
  float mean = s * (1.f / 2048.f);
  float ss = 0.f;
  #pragma unroll
  for (int j = 0; j < 8; ++j) { float d = v[j] - mean; ss = fmaf(d, d, ss); }
  ss = block_sum256(ss, sh);
  float rstd = rsqrtf(ss * (1.f / 2048.f) + 1e-5f);
  #pragma unroll
  for (int j = 0; j < 8; ++j) {
    int f = threadIdx.x + 256 * j;
    int hh = f >> 9, dd = f & 511;
    float o = (v[j] - mean) * rstd * gam[f] + bet[f];
    if (!transposed)
      outp[(((size_t)b * 4 + hh) * 32 + l) * 512 + dd] = f2bf(o);
    else
      outp[(((size_t)b * 4 + hh) * 512 + dd) * 32 + l] = f2bf(o);
  }
}

// ---------------- MFMA fused attention per (b,h,g) --------------------------
// Scores S[16x64] = Q[16x512] x Ks[64x512]^T via mfma (cols: 0..31 compress,
// 32..51 window, 52..63 pad). PV: compress part one-K-step MFMA with B-frags
// straight from global VcT (coalesced); window part VALU in MFMA layout.
// Cf aliases Qf (reads precede writes; blocks disjoint).
__global__ __launch_bounds__(256)
void attn_mfma(const bf16_t* __restrict__ Qf, const bf16_t* __restrict__ Kf,
               const bf16_t* __restrict__ Vf, const bf16_t* __restrict__ KcB,
               const bf16_t* __restrict__ VcT, const float* __restrict__ mask,
               bf16_t* __restrict__ Cf) {
  int g = blockIdx.x % GGN;
  int bh = blockIdx.x / GGN;
  int h = bh & 3, b = bh >> 2;
  __shared__ bf16_t Qs[16 * 136];       // chunk [16][128] stride 136
  __shared__ bf16_t KV[10400];          // Ks [64][136] | Vw [20][520]
  __shared__ float sc[16][68];
  __shared__ bf16_t Ps[16 * 40];        // P compress cols bf16, stride 40
  __shared__ float colvalid[TTN];
  bf16_t* Ks = KV;
  bf16_t* Vw = KV;
  int tid = threadIdx.x;
  int wave = tid >> 6, lane = tid & 63;
  int quad = lane >> 4, ml = lane & 15;

  if (tid < TTN) {
    int j = g * WSZ + tid - EXTT;
    colvalid[tid] = (j >= 0 && j < SS && mask[(size_t)b * SS + j] != 0.f) ? 1.f : 0.f;
  }

  size_t qbase = ((size_t)b * SS + g * WSZ) * HDK + h * DKK;
  floatx4 sacc;
  #pragma unroll
  for (int r = 0; r < 4; ++r) sacc[r] = 0.f;

  // ---- score phase: 4 d-chunks of 128 ----
  for (int ch = 0; ch < 4; ++ch) {
    {
      int row = tid >> 4, c8 = tid & 15;
      uint4 v = {0, 0, 0, 0};
      if (row < WSZ)
        v = *(const uint4*)&Qf[qbase + (size_t)row * HDK + ch * 128 + c8 * 8];
      *(uint4*)&Qs[row * 136 + c8 * 8] = v;
    }
    #pragma unroll
    for (int ii = 0; ii < 4; ++ii) {
      int idx = ii * 256 + tid;
      int row = idx >> 4, c8 = idx & 15;
      uint4 v = {0, 0, 0, 0};
      if (row < 32) {
        v = *(const uint4*)&KcB[(((size_t)b * 4 + h) * 32 + row) * 512 + ch * 128 + c8 * 8];
      } else if (row < 52) {
        int j = g * WSZ + (row - 32) - EXTT;
        if (j >= 0 && j < SS)
          v = *(const uint4*)&Kf[((size_t)b * SS + j) * HDK + h * DKK + ch * 128 + c8 * 8];
      }
      *(uint4*)&Ks[row * 136 + c8 * 8] = v;
    }
    __syncthreads();
    #pragma unroll
    for (int ks = 0; ks < 4; ++ks) {
      short8 af = *(const short8*)&Qs[ml * 136 + ks * 32 + quad * 8];
      short8 bf = *(const short8*)&Ks[(wave * 16 + ml) * 136 + ks * 32 + quad * 8];
      sacc = __builtin_amdgcn_mfma_f32_16x16x32_bf16(af, bf, sacc, 0, 0, 0);
    }
    __syncthreads();
  }
  // write scores (C layout: row=quad*4+r, col=wave*16+ml), zero Ps, stage Vw
  #pragma unroll
  for (int r = 0; r < 4; ++r) sc[quad * 4 + r][wave * 16 + ml] = sacc[r];
  for (int i = tid; i < 16 * 40; i += 256) Ps[i] = 0;
  #pragma unroll
  for (int ii = 0; ii < 5; ++ii) {
    int idx = ii * 256 + tid;               // 1280 = 20 rows x 64 c8
    int t = idx >> 6, c8 = idx & 63;
    int j = g * WSZ + t - EXTT;
    uint4 v = {0, 0, 0, 0};
    if (j >= 0 && j < SS)
      v = *(const uint4*)&Vf[((size_t)b * SS + j) * HDK + h * DKK + c8 * 8];
    *(uint4*)&Vw[t * 520 + c8 * 8] = v;
  }
  __syncthreads();
  // ---- softmax rows 0..9 ----
  if (tid < WSZ) {
    float mx = -INFINITY;
    for (int c = 0; c < 52; ++c) {
      float v = sc[tid][c];
      bool valid = (c < NLL) || (colvalid[c - NLL] != 0.f);
      v = valid ? v : -INFINITY;
      sc[tid][c] = v;
      mx = fmaxf(mx, v);
    }
    float sum = 0.f;
    for (int c = 0; c < 52; ++c) { float e = expf(sc[tid][c] - mx); sc[tid][c] = e; sum += e; }
    float qm = mask[(size_t)b * SS + g * WSZ + tid];
    float inv = (qm != 0.f) ? 1.f / sum : 0.f;
    for (int c = 0; c < 52; ++c) {
      float p = sc[tid][c] * inv;
      sc[tid][c] = p;
      if (c < NLL) Ps[tid * 40 + c] = f2bf(p);
    }
  }
  __syncthreads();
  // ---- PV phase ----
  short8 paf = *(const short8*)&Ps[ml * 40 + quad * 8];
  size_t vctbase = (((size_t)b * 4 + h) * 512) * 32;
  #pragma unroll
  for (int nt = 0; nt < 8; ++nt) {
    int d = wave * 128 + nt * 16 + ml;
    short8 vbf = *(const short8*)&VcT[vctbase + (size_t)d * 32 + quad * 8];
    floatx4 oacc;
    #pragma unroll
    for (int r = 0; r < 4; ++r) oacc[r] = 0.f;
    oacc = __builtin_amdgcn_mfma_f32_16x16x32_bf16(paf, vbf, oacc, 0, 0, 0);
    float wsum[4] = {0.f, 0.f, 0.f, 0.f};
    #pragma unroll
    for (int t = 0; t < TTN; ++t) {
      float vv = bf2f(Vw[t * 520 + d]);
      #pragma unroll
      for (int r = 0; r < 4; ++r)
        wsum[r] = fmaf(sc[quad * 4 + r][NLL + t], vv, wsum[r]);
    }
    #pragma unroll
    for (int r = 0; r < 4; ++r) {
      int row = quad * 4 + r;
      if (row < WSZ)
        Cf[qbase + (size_t)row * HDK + d] = f2bf(oacc[r] + wsum[r]);
    }
  }
}

extern "C" void kernel_launch(void* const* d_in, const int* in_sizes, int n_in,
                              void* d_out, int out_size, void* d_ws, size_t ws_size,
                              hipStream_t stream) {
  const float* X     = (const float*)d_in[0];
  const float* mask  = (const float*)d_in[3];
  const float* Wq    = (const float*)d_in[4];
  const float* bq    = (const float*)d_in[5];
  const float* Wk    = (const float*)d_in[6];
  const float* bk    = (const float*)d_in[7];
  const float* Wv    = (const float*)d_in[8];
  const float* bv    = (const float*)d_in[9];
  const float* Wo    = (const float*)d_in[10];
  const float* bo    = (const float*)d_in[11];
  const float* Wd    = (const float*)d_in[12];
  const float* bd    = (const float*)d_in[13];
  const float* lnl_g = (const float*)d_in[14];
  const float* lnl_b = (const float*)d_in[15];
  const float* lns_g = (const float*)d_in[16];
  const float* lns_b = (const float*)d_in[17];
  float* out = (float*)d_out;

  // workspace carve (bytes): total ~209 MB (proven safe R2-R8)
  char* ws = (char*)d_ws;
  bf16_t* Q   = (bf16_t*)(ws);                 // 65,536,000 B
  bf16_t* K   = (bf16_t*)(ws + 65536000);      // 65,536,000 B
  bf16_t* V   = (bf16_t*)(ws + 131072000);     // 65,536,000 B
  float*  hs  = (float*) (ws + 196608000);     // 8,192,000 B
  float*  Kc  = (float*) (ws + 204800000);     // 2,097,152 B
  float*  Vc  = (float*) (ws + 206897152);     // 2,097,152 B
  bf16_t* C   = Q;                             // alias (see attn_mfma note)
  // transient bf16 B^T weights in dead regions:
  bf16_t* Wqt = (bf16_t*)(ws + 196608000);           // hs region (pre-hs-GEMM)
  bf16_t* Wkt = (bf16_t*)(ws + 196608000 + 2097152);
  bf16_t* Wvt = (bf16_t*)(ws + 196608000 + 4194304);
  bf16_t* Wdt = (bf16_t*)(ws + 204800000);           // Kc region (pre-memset)
  bf16_t* Wot = (bf16_t*)(ws + 65536000);            // K region (post-attn)
  // bf16 LN'd compress tensors in hs region (dead after compress_atomic).
  // Each is 8*4*32*512 elements = 1,048,576 BYTES (R8 bug: had +262144 overlap)
  bf16_t* KcB = (bf16_t*)(ws + 196608000);            // 1,048,576 B
  bf16_t* VcT = (bf16_t*)(ws + 196608000 + 1048576);  // 1,048,576 B

  const float scale = 0.04419417382415922f;  // 1/sqrt(512)
  const dim3 blk(256);

  // 1. transpose weights to bf16 B^T
  transpose_w<<<dim3(32, 8), blk, 0, stream>>>(Wq, Wqt, 512, 2048);
  transpose_w<<<dim3(32, 8), blk, 0, stream>>>(Wk, Wkt, 512, 2048);
  transpose_w<<<dim3(32, 8), blk, 0, stream>>>(Wv, Wvt, 512, 2048);
  transpose_w<<<dim3(2, 8),  blk, 0, stream>>>(Wd, Wdt, 512, 128);
  // 2. Q/K/V projections (MFMA)
  gemm_mfma<float, bf16_t><<<dim3(16, 125), blk, 0, stream>>>(X, Wqt, bq, Q, MMR, 2048, 512, scale);
  gemm_mfma<float, bf16_t><<<dim3(16, 125), blk, 0, stream>>>(X, Wkt, bk, K, MMR, 2048, 512, 1.f);
  gemm_mfma<float, bf16_t><<<dim3(16, 125), blk, 0, stream>>>(X, Wvt, bv, V, MMR, 2048, 512, 1.f);
  // 3. hs projection (overwrites Wqt region; reads Wdt)
  gemm_mfma<float, float ><<<dim3(1, 125),  blk, 0, stream>>>(X, Wdt, bd, hs, MMR, 128, 512, 1.f);
  // 4. LN on K,V rows; hs softmax
  ln2048_bf16<<<MMR, blk, 0, stream>>>(K, lnl_g, lnl_b);
  ln2048_bf16<<<MMR, blk, 0, stream>>>(V, lnl_g, lnl_b);
  hs_softmax_par<<<BB * 8, blk, 0, stream>>>(hs, mask);
  // 5. landmark compression (memset overwrites Wdt — already consumed)
  hipMemsetAsync(ws + 204800000, 0, 4194304, stream);
  compress_atomic<<<512, blk, 0, stream>>>(K, V, hs, Kc, Vc);
  // 6. LN on compressed rows -> bf16 KcB (row) and VcT (transposed); hs dead
  ln_comp_out<<<BB * NLL, blk, 0, stream>>>(Kc, lns_g, lns_b, KcB, 0);
  ln_comp_out<<<BB * NLL, blk, 0, stream>>>(Vc, lns_g, lns_b, VcT, 1);
  // 7. fused MFMA attention (writes C = alias of Q)
  attn_mfma<<<BB * HHN * GGN, blk, 0, stream>>>(Q, K, V, KcB, VcT, mask, C);
  // 8. transpose Wo into dead K region, then output projection (MFMA)
  transpose_w<<<dim3(8, 32), blk, 0, stream>>>(Wo, Wot, 2048, 512);
  gemm_mfma<bf16_t, float><<<dim3(4, 125), blk, 0, stream>>>(C, Wot, bo, out, MMR, 512, 2048, 1.f);
}